// Round 9
// baseline (94.372 us; speedup 1.0000x reference)
//
#include <hip/hip_runtime.h>

// NT-Xent (SimCLR) loss, B=2048, D=256, N=4096, T=0.5, eps=1e-8.
// R9: R8's ticket/fence fusion regressed (+11us) -> back to R6's 3-launch
// structure. New lever: k_simlse is latency-bound (~21us; halving FLOPs in
// R3 saved only 2us) with just 528 blocks = 2/CU co-residency. Shrink tiles
// 128 -> 64: 2080 triangle blocks (~8/CU) hides the ~900cyc cross-XCD zn
// staging latency with TLP. Per-wave 16x64 stripe -> simpler epilogue
// (no cross-wave row reduce; 4-way LDS col reduce).
// Fixed harness floor: ~42us d_ws poison fill + d_in restore per iter.

#define NROWS 4096
#define DDIM 256
#define BHALF 2048
#define TILE 64
#define BK 64
#define LDP 72      // padded LDS row stride (shorts): 144B = 9*16B, 2-way banks (free)
#define NCB 64      // 4096/64 tile indices
#define NBLK (NCB * (NCB + 1) / 2)   // 2080
#define INV_T 2.0f

typedef short bf16x8 __attribute__((ext_vector_type(8)));
typedef float f32x4 __attribute__((ext_vector_type(4)));

__device__ inline unsigned short f2bf(float f) {
    union { float f; unsigned u; } c; c.f = f;
    unsigned u = c.u + 0x7fffu + ((c.u >> 16) & 1u);  // RNE
    return (unsigned short)(u >> 16);
}

// ---- Kernel 1: row-normalize z=[z_i;z_j] into bf16 zn[4096][256] ----------
__global__ __launch_bounds__(256) void k_normalize(
    const float* __restrict__ zi, const float* __restrict__ zj,
    unsigned short* __restrict__ zn, float* __restrict__ out) {
    if (blockIdx.x == 0 && threadIdx.x == 0) out[0] = 0.f;  // for rowlse atomics
    const int wave = threadIdx.x >> 6, lane = threadIdx.x & 63;
    const int row = blockIdx.x * 4 + wave;
    const float* src = (row < BHALF) ? (zi + row * DDIM)
                                     : (zj + (row - BHALF) * DDIM);
    const float4 v = ((const float4*)src)[lane];
    float ss = v.x * v.x + v.y * v.y + v.z * v.z + v.w * v.w;
    #pragma unroll
    for (int m = 1; m < 64; m <<= 1) ss += __shfl_xor(ss, m);
    const float scale = 1.0f / fmaxf(sqrtf(ss), 1e-8f);
    ushort4 o;
    o.x = f2bf(v.x * scale); o.y = f2bf(v.y * scale);
    o.z = f2bf(v.z * scale); o.w = f2bf(v.w * scale);
    ((ushort4*)(zn + row * DDIM))[lane] = o;
}

// ---- Kernel 2: upper-triangle 64x64 LDS-tiled sim GEMM + exp-sums ---------
// grid = 2080 blocks -> (bx,by), by>=bx. Block 256 thr = 4 waves; wave w
// computes the 16-row stripe [w*16,+16) x all 64 cols via 1x4
// mfma_f32_16x16x32_bf16.
__global__ __launch_bounds__(256) void k_simlse(
    const unsigned short* __restrict__ zn,
    float* __restrict__ partial,     // [NCB][4096], each slot 1 writer
    float* __restrict__ posv) {      // [4096]
    __shared__ unsigned short As[TILE * LDP];
    __shared__ unsigned short Bs[TILE * LDP];
    __shared__ float cscratch[4 * TILE];   // per-wave col sums

    // triangle decode: block t -> (bx, by), by >= bx
    int t = blockIdx.x, bx = 0, rem = NCB;
    while (t >= rem) { t -= rem; ++bx; --rem; }
    const int by = bx + t;

    const int tid = threadIdx.x;
    const int wave = tid >> 6, lane = tid & 63;
    const int quad = lane >> 4, l15 = lane & 15;
    const int rowBase = bx * TILE;
    const int colBase = by * TILE;

    f32x4 acc[4] = {};   // [nt]

    #pragma unroll
    for (int kb = 0; kb < DDIM / BK; ++kb) {
        __syncthreads();
        #pragma unroll
        for (int i = 0; i < 2; ++i) {
            const int flat = tid + i * 256;        // 0..511
            const int r = flat >> 3, c = flat & 7; // row 0..63, 8-short chunk
            *(bf16x8*)&As[r * LDP + c * 8] =
                *(const bf16x8*)&zn[(rowBase + r) * DDIM + kb * BK + c * 8];
            *(bf16x8*)&Bs[r * LDP + c * 8] =
                *(const bf16x8*)&zn[(colBase + r) * DDIM + kb * BK + c * 8];
        }
        __syncthreads();
        #pragma unroll
        for (int s = 0; s < 2; ++s) {
            const bf16x8 af =
                *(const bf16x8*)&As[(wave * 16 + l15) * LDP + s * 32 + quad * 8];
            bf16x8 bf[4];
            #pragma unroll
            for (int nt = 0; nt < 4; ++nt)
                bf[nt] = *(const bf16x8*)&Bs[(nt * 16 + l15) * LDP + s * 32 + quad * 8];
            #pragma unroll
            for (int nt = 0; nt < 4; ++nt)
                acc[nt] = __builtin_amdgcn_mfma_f32_16x16x32_bf16(
                    af, bf[nt], acc[nt], 0, 0, 0);
        }
    }

    // Epilogue. C/D layout: col = lane&15, row = quad*4 + r (within stripe).
    const int wrow = rowBase + wave * 16;
    float rsum[4];
    float csum[4] = {};
    #pragma unroll
    for (int r = 0; r < 4; ++r) {
        const int grow = wrow + quad * 4 + r;
        float s = 0.f;
        #pragma unroll
        for (int nt = 0; nt < 4; ++nt) {
            const int gcol = colBase + nt * 16 + l15;
            const float simv = acc[nt][r] * INV_T;
            const float e = (gcol != grow) ? __expf(simv) : 0.f;
            s += e;
            csum[nt] += e;
            if (gcol == grow + BHALF) {   // only in by==bx+32 blocks
                posv[grow] = simv;        // sim symmetric -> both rows
                posv[gcol] = simv;
            }
        }
        s += __shfl_xor(s, 1); s += __shfl_xor(s, 2);
        s += __shfl_xor(s, 4); s += __shfl_xor(s, 8);
        rsum[r] = s;
    }
    // col sums: reduce over the stripe's 16 rows (lane bits 4,5)
    #pragma unroll
    for (int nt = 0; nt < 4; ++nt) {
        csum[nt] += __shfl_xor(csum[nt], 16);
        csum[nt] += __shfl_xor(csum[nt], 32);
    }

    // row-sums -> partial[by][wrow..] (each wave owns its 16 rows)
    if (l15 == 0) {
        #pragma unroll
        for (int r = 0; r < 4; ++r)
            partial[by * NROWS + wrow + quad * 4 + r] = rsum[r];
    }
    // col-sums: 4-way cross-wave reduce in LDS, then one writer per col
    if (quad == 0) {
        #pragma unroll
        for (int nt = 0; nt < 4; ++nt)
            cscratch[wave * TILE + nt * 16 + l15] = csum[nt];
    }
    __syncthreads();
    if (bx != by && tid < TILE) {
        const float cs = cscratch[tid] + cscratch[TILE + tid]
                       + cscratch[2 * TILE + tid] + cscratch[3 * TILE + tid];
        partial[bx * NROWS + colBase + tid] = cs;
    }
}

// ---- Kernel 3: 16-block rowlse + atomic final sum -------------------------
__global__ __launch_bounds__(256) void k_rowlse(
    const float* __restrict__ partial, const float* __restrict__ posv,
    float* __restrict__ out) {
    __shared__ float red[4];
    const int tid = threadIdx.x;
    const int row = blockIdx.x * 256 + tid;
    float s = 0.f;
    #pragma unroll
    for (int p = 0; p < NCB; ++p) s += partial[p * NROWS + row];
    float v = __logf(s) - posv[row];
    #pragma unroll
    for (int m = 1; m < 64; m <<= 1) v += __shfl_xor(v, m);
    if ((tid & 63) == 0) red[tid >> 6] = v;
    __syncthreads();
    if (tid == 0)
        atomicAdd(out, (red[0] + red[1] + red[2] + red[3]) * (1.0f / (float)NROWS));
}

extern "C" void kernel_launch(void* const* d_in, const int* in_sizes, int n_in,
                              void* d_out, int out_size, void* d_ws, size_t ws_size,
                              hipStream_t stream) {
    const float* zi = (const float*)d_in[0];
    const float* zj = (const float*)d_in[1];
    float* out = (float*)d_out;

    unsigned short* zn = (unsigned short*)d_ws;                    // 2 MB
    float* partial = (float*)((char*)d_ws + NROWS * DDIM * 2);     // 1 MB
    float* posv = partial + NCB * NROWS;                           // 16 KB

    k_normalize<<<NROWS / 4, 256, 0, stream>>>(zi, zj, zn, out);
    k_simlse<<<NBLK, 256, 0, stream>>>(zn, partial, posv);
    k_rowlse<<<16, 256, 0, stream>>>(partial, posv, out);
}

// Round 10
// 87.267 us; speedup vs baseline: 1.0814x; 1.0814x over previous
//
#include <hip/hip_runtime.h>

// NT-Xent (SimCLR) loss, B=2048, D=256, N=4096, T=0.5, eps=1e-8.
// R10: R6 structure (best: 77.7us; all structural gambles R4/5/7/8/9 lost).
// Change: exp-sums accumulate via device-scope atomicAdd into rowsum[4096]
// (replaces partial[32][4096] store + 64-way rowlse gather). Simpler simlse
// epilogue (no LDS scratch, 2 fewer barriers); rowlse reads 16KB not 1MB.
// Fixed harness floor: ~41.5us d_ws poison fill + restores + replay overhead.

#define NROWS 4096
#define DDIM 256
#define BHALF 2048
#define TILE 128
#define BK 64
#define LDP 72      // padded LDS row stride (shorts): 144B = 9*16B, 2-way banks (free)
#define NCB 32      // 4096/128 tile indices
#define NBLK (NCB * (NCB + 1) / 2)   // 528
#define INV_T 2.0f

typedef short bf16x8 __attribute__((ext_vector_type(8)));
typedef float f32x4 __attribute__((ext_vector_type(4)));

__device__ inline unsigned short f2bf(float f) {
    union { float f; unsigned u; } c; c.f = f;
    unsigned u = c.u + 0x7fffu + ((c.u >> 16) & 1u);  // RNE
    return (unsigned short)(u >> 16);
}

// ---- Kernel 1: row-normalize z -> bf16 zn; zero rowsum & out --------------
__global__ __launch_bounds__(256) void k_normalize(
    const float* __restrict__ zi, const float* __restrict__ zj,
    unsigned short* __restrict__ zn, float* __restrict__ rowsum,
    float* __restrict__ out) {
    if (threadIdx.x < 4) rowsum[blockIdx.x * 4 + threadIdx.x] = 0.f;
    if (blockIdx.x == 0 && threadIdx.x == 4) out[0] = 0.f;
    const int wave = threadIdx.x >> 6, lane = threadIdx.x & 63;
    const int row = blockIdx.x * 4 + wave;
    const float* src = (row < BHALF) ? (zi + row * DDIM)
                                     : (zj + (row - BHALF) * DDIM);
    const float4 v = ((const float4*)src)[lane];
    float ss = v.x * v.x + v.y * v.y + v.z * v.z + v.w * v.w;
    #pragma unroll
    for (int m = 1; m < 64; m <<= 1) ss += __shfl_xor(ss, m);
    const float scale = 1.0f / fmaxf(sqrtf(ss), 1e-8f);
    ushort4 o;
    o.x = f2bf(v.x * scale); o.y = f2bf(v.y * scale);
    o.z = f2bf(v.z * scale); o.w = f2bf(v.w * scale);
    ((ushort4*)(zn + row * DDIM))[lane] = o;
}

// ---- Kernel 2: upper-triangle LDS-tiled sim GEMM + atomic exp-sums --------
// grid = 528 blocks -> (bx,by), by>=bx; 256 thr = 2x2 waves, wave = 64x64.
__global__ __launch_bounds__(256) void k_simlse(
    const unsigned short* __restrict__ zn,
    float* __restrict__ rowsum,      // [4096], atomic accumulate
    float* __restrict__ posv) {      // [4096]
    __shared__ unsigned short As[TILE * LDP];
    __shared__ unsigned short Bs[TILE * LDP];

    // triangle decode: block t -> (bx, by), by >= bx
    int t = blockIdx.x, bx = 0, rem = NCB;
    while (t >= rem) { t -= rem; ++bx; --rem; }
    const int by = bx + t;

    const int tid = threadIdx.x;
    const int wave = tid >> 6, lane = tid & 63;
    const int quad = lane >> 4, l15 = lane & 15;
    const int wr = wave >> 1, wc = wave & 1;
    const int rowBase = bx * TILE;
    const int colBase = by * TILE;

    f32x4 acc[4][4] = {};

    #pragma unroll
    for (int kb = 0; kb < DDIM / BK; ++kb) {
        __syncthreads();
        #pragma unroll
        for (int i = 0; i < 4; ++i) {
            const int flat = tid + i * 256;
            const int r = flat >> 3, c = flat & 7;
            *(bf16x8*)&As[r * LDP + c * 8] =
                *(const bf16x8*)&zn[(rowBase + r) * DDIM + kb * BK + c * 8];
            *(bf16x8*)&Bs[r * LDP + c * 8] =
                *(const bf16x8*)&zn[(colBase + r) * DDIM + kb * BK + c * 8];
        }
        __syncthreads();
        #pragma unroll
        for (int s = 0; s < 2; ++s) {
            bf16x8 af[4], bf[4];
            #pragma unroll
            for (int mt = 0; mt < 4; ++mt)
                af[mt] = *(const bf16x8*)&As[(wr * 64 + mt * 16 + l15) * LDP + s * 32 + quad * 8];
            #pragma unroll
            for (int nt = 0; nt < 4; ++nt)
                bf[nt] = *(const bf16x8*)&Bs[(wc * 64 + nt * 16 + l15) * LDP + s * 32 + quad * 8];
            #pragma unroll
            for (int mt = 0; mt < 4; ++mt)
                #pragma unroll
                for (int nt = 0; nt < 4; ++nt)
                    acc[mt][nt] = __builtin_amdgcn_mfma_f32_16x16x32_bf16(
                        af[mt], bf[nt], acc[mt][nt], 0, 0, 0);
        }
    }

    // Epilogue. C/D layout: col = lane&15, row = quad*4 + r.
    float rsum[4][4];          // [mt][r] row-sums over this wave's 64 cols
    float csum[4] = {};        // [nt] per-lane col partials
    #pragma unroll
    for (int mt = 0; mt < 4; ++mt) {
        #pragma unroll
        for (int r = 0; r < 4; ++r) {
            const int grow = rowBase + wr * 64 + mt * 16 + quad * 4 + r;
            float s = 0.f;
            #pragma unroll
            for (int nt = 0; nt < 4; ++nt) {
                const int gcol = colBase + wc * 64 + nt * 16 + l15;
                const float simv = acc[mt][nt][r] * INV_T;
                const float e = (gcol != grow) ? __expf(simv) : 0.f;
                s += e;
                csum[nt] += e;
                if (gcol == grow + BHALF) {       // only in by==bx+16 blocks
                    posv[grow] = simv;            // sim symmetric -> both rows
                    posv[gcol] = simv;
                }
            }
            s += __shfl_xor(s, 1); s += __shfl_xor(s, 2);
            s += __shfl_xor(s, 4); s += __shfl_xor(s, 8);
            rsum[mt][r] = s;
        }
    }
    // col sums: reduce across quads (lane bits 4,5) -> wave's 64 rows total
    #pragma unroll
    for (int nt = 0; nt < 4; ++nt) {
        csum[nt] += __shfl_xor(csum[nt], 16);
        csum[nt] += __shfl_xor(csum[nt], 32);
    }

    // Device-scope atomic accumulation (G12: 4096 addrs, ~64 adds each).
    if (l15 == 0) {    // lanes 0,16,32,48 = quads 0..3
        #pragma unroll
        for (int mt = 0; mt < 4; ++mt)
            #pragma unroll
            for (int r = 0; r < 4; ++r)
                atomicAdd(&rowsum[rowBase + wr * 64 + mt * 16 + quad * 4 + r],
                          rsum[mt][r]);
    }
    if (bx != by && quad == 0) {
        #pragma unroll
        for (int nt = 0; nt < 4; ++nt)
            atomicAdd(&rowsum[colBase + wc * 64 + nt * 16 + l15], csum[nt]);
    }
}

// ---- Kernel 3: 16-block rowlse + atomic final sum -------------------------
__global__ __launch_bounds__(256) void k_rowlse(
    const float* __restrict__ rowsum, const float* __restrict__ posv,
    float* __restrict__ out) {
    __shared__ float red[4];
    const int tid = threadIdx.x;
    const int row = blockIdx.x * 256 + tid;
    float v = __logf(rowsum[row]) - posv[row];
    #pragma unroll
    for (int m = 1; m < 64; m <<= 1) v += __shfl_xor(v, m);
    if ((tid & 63) == 0) red[tid >> 6] = v;
    __syncthreads();
    if (tid == 0)
        atomicAdd(out, (red[0] + red[1] + red[2] + red[3]) * (1.0f / (float)NROWS));
}

extern "C" void kernel_launch(void* const* d_in, const int* in_sizes, int n_in,
                              void* d_out, int out_size, void* d_ws, size_t ws_size,
                              hipStream_t stream) {
    const float* zi = (const float*)d_in[0];
    const float* zj = (const float*)d_in[1];
    float* out = (float*)d_out;

    unsigned short* zn = (unsigned short*)d_ws;                    // 2 MB
    float* rowsum = (float*)((char*)d_ws + NROWS * DDIM * 2);      // 16 KB
    float* posv = rowsum + NROWS;                                  // 16 KB

    k_normalize<<<NROWS / 4, 256, 0, stream>>>(zi, zj, zn, rowsum, out);
    k_simlse<<<NBLK, 256, 0, stream>>>(zn, rowsum, posv);
    k_rowlse<<<16, 256, 0, stream>>>(rowsum, posv, out);
}

// Round 11
// 78.806 us; speedup vs baseline: 1.1975x; 1.1074x over previous
//
#include <hip/hip_runtime.h>

// NT-Xent (SimCLR) loss, B=2048, D=256, N=4096, T=0.5, eps=1e-8.
// R11: revert to R6 — the measured optimum (77.7us). All structural
// deviations regressed: R4 fused-normalize 125, R5 1-block finalize 107,
// R7 cooperative fail, R8 ticket/fence 88.5, R9 64-tiles 94.4, R10
// atomic-rowsum 87.3. The dominant timed dispatch is the harness's 256MB
// d_ws poison fill at ~6.5TB/s (HBM ceiling); our 3 kernels are ~8-10us
// against a ~68us fixed harness floor.
// Structure: normalize -> bf16 zn (L2-resident) | upper-triangle 128x128
// LDS-tiled MFMA sim GEMM + fused exp-sums (row+col via symmetry) |
// 16-block rowlse + atomicAdd(out) (out zeroed in k_normalize).

#define NROWS 4096
#define DDIM 256
#define BHALF 2048
#define TILE 128
#define BK 64
#define LDP 72      // padded LDS row stride (shorts): 144B = 9*16B, 2-way banks (free)
#define NCB 32      // 4096/128 tile indices
#define INV_T 2.0f

typedef short bf16x8 __attribute__((ext_vector_type(8)));
typedef float f32x4 __attribute__((ext_vector_type(4)));

__device__ inline unsigned short f2bf(float f) {
    union { float f; unsigned u; } c; c.f = f;
    unsigned u = c.u + 0x7fffu + ((c.u >> 16) & 1u);  // RNE
    return (unsigned short)(u >> 16);
}

// ---- Kernel 1: row-normalize z=[z_i;z_j] into bf16 zn[4096][256] ----------
__global__ __launch_bounds__(256) void k_normalize(
    const float* __restrict__ zi, const float* __restrict__ zj,
    unsigned short* __restrict__ zn, float* __restrict__ out) {
    if (blockIdx.x == 0 && threadIdx.x == 0) out[0] = 0.f;  // for k_rowlse atomics
    const int wave = threadIdx.x >> 6, lane = threadIdx.x & 63;
    const int row = blockIdx.x * 4 + wave;
    const float* src = (row < BHALF) ? (zi + row * DDIM)
                                     : (zj + (row - BHALF) * DDIM);
    const float4 v = ((const float4*)src)[lane];
    float ss = v.x * v.x + v.y * v.y + v.z * v.z + v.w * v.w;
    #pragma unroll
    for (int m = 1; m < 64; m <<= 1) ss += __shfl_xor(ss, m);
    const float scale = 1.0f / fmaxf(sqrtf(ss), 1e-8f);
    ushort4 o;
    o.x = f2bf(v.x * scale); o.y = f2bf(v.y * scale);
    o.z = f2bf(v.z * scale); o.w = f2bf(v.w * scale);
    ((ushort4*)(zn + row * DDIM))[lane] = o;
}

// ---- Kernel 2: upper-triangle LDS-tiled sim GEMM + exp-sum ----------------
// grid = 528 linear blocks -> (bx,by), by>=bx. Block 256 thr = 2x2 waves,
// each wave 64x64 via 4x4 mfma_f32_16x16x32_bf16.
__global__ __launch_bounds__(256) void k_simlse(
    const unsigned short* __restrict__ zn,
    float* __restrict__ partial,     // [NCB][4096], each slot 1 writer
    float* __restrict__ posv) {      // [4096]
    __shared__ unsigned short As[TILE * LDP];
    __shared__ unsigned short Bs[TILE * LDP];
    __shared__ float pscratch[TILE];   // row sums cross-wc
    __shared__ float cscratch[TILE];   // col sums cross-wr

    // triangle decode: block t -> (bx, by), by >= bx
    int t = blockIdx.x, bx = 0, rem = NCB;
    while (t >= rem) { t -= rem; ++bx; --rem; }
    const int by = bx + t;

    const int tid = threadIdx.x;
    const int wave = tid >> 6, lane = tid & 63;
    const int quad = lane >> 4, l15 = lane & 15;
    const int wr = wave >> 1, wc = wave & 1;
    const int rowBase = bx * TILE;
    const int colBase = by * TILE;

    f32x4 acc[4][4] = {};

    #pragma unroll
    for (int kb = 0; kb < DDIM / BK; ++kb) {
        __syncthreads();
        #pragma unroll
        for (int i = 0; i < 4; ++i) {
            const int flat = tid + i * 256;
            const int r = flat >> 3, c = flat & 7;
            *(bf16x8*)&As[r * LDP + c * 8] =
                *(const bf16x8*)&zn[(rowBase + r) * DDIM + kb * BK + c * 8];
            *(bf16x8*)&Bs[r * LDP + c * 8] =
                *(const bf16x8*)&zn[(colBase + r) * DDIM + kb * BK + c * 8];
        }
        __syncthreads();
        #pragma unroll
        for (int s = 0; s < 2; ++s) {
            bf16x8 af[4], bf[4];
            #pragma unroll
            for (int mt = 0; mt < 4; ++mt)
                af[mt] = *(const bf16x8*)&As[(wr * 64 + mt * 16 + l15) * LDP + s * 32 + quad * 8];
            #pragma unroll
            for (int nt = 0; nt < 4; ++nt)
                bf[nt] = *(const bf16x8*)&Bs[(wc * 64 + nt * 16 + l15) * LDP + s * 32 + quad * 8];
            #pragma unroll
            for (int mt = 0; mt < 4; ++mt)
                #pragma unroll
                for (int nt = 0; nt < 4; ++nt)
                    acc[mt][nt] = __builtin_amdgcn_mfma_f32_16x16x32_bf16(
                        af[mt], bf[nt], acc[mt][nt], 0, 0, 0);
        }
    }

    // Epilogue. C/D layout: col = lane&15, row = quad*4 + r.
    float rsum[4][4];          // [mt][r] row-sums (post-butterfly: all lanes)
    float csum[4] = {};        // [nt] per-lane col partial over 16 rows
    #pragma unroll
    for (int mt = 0; mt < 4; ++mt) {
        #pragma unroll
        for (int r = 0; r < 4; ++r) {
            const int grow = rowBase + wr * 64 + mt * 16 + quad * 4 + r;
            float s = 0.f;
            #pragma unroll
            for (int nt = 0; nt < 4; ++nt) {
                const int gcol = colBase + wc * 64 + nt * 16 + l15;
                const float simv = acc[mt][nt][r] * INV_T;
                const float e = (gcol != grow) ? __expf(simv) : 0.f;
                s += e;
                csum[nt] += e;
                if (gcol == grow + BHALF) {       // only in by==bx+16 blocks
                    posv[grow] = simv;            // sim symmetric -> both rows
                    posv[gcol] = simv;
                }
            }
            s += __shfl_xor(s, 1); s += __shfl_xor(s, 2);
            s += __shfl_xor(s, 4); s += __shfl_xor(s, 8);
            rsum[mt][r] = s;
        }
    }
    // col reduce across quads (row-index bits 4,5 of lane)
    #pragma unroll
    for (int nt = 0; nt < 4; ++nt) {
        csum[nt] += __shfl_xor(csum[nt], 16);
        csum[nt] += __shfl_xor(csum[nt], 32);
    }

    __syncthreads();
    if (wc == 0 && l15 == 0) {
        #pragma unroll
        for (int mt = 0; mt < 4; ++mt)
            #pragma unroll
            for (int r = 0; r < 4; ++r)
                pscratch[wr * 64 + mt * 16 + quad * 4 + r] = rsum[mt][r];
    }
    if (wr == 0 && quad == 0) {
        #pragma unroll
        for (int nt = 0; nt < 4; ++nt)
            cscratch[wc * 64 + nt * 16 + l15] = csum[nt];
    }
    __syncthreads();
    if (wc == 1 && l15 == 0) {    // row-sums -> partial[by][rowBase..]
        #pragma unroll
        for (int mt = 0; mt < 4; ++mt)
            #pragma unroll
            for (int r = 0; r < 4; ++r) {
                const int lr = wr * 64 + mt * 16 + quad * 4 + r;
                partial[by * NROWS + rowBase + lr] = rsum[mt][r] + pscratch[lr];
            }
    }
    if (bx != by && wr == 1 && quad == 0) {  // col-sums -> partial[bx][colBase..]
        #pragma unroll
        for (int nt = 0; nt < 4; ++nt) {
            const int lc = wc * 64 + nt * 16 + l15;
            partial[bx * NROWS + colBase + lc] = csum[nt] + cscratch[lc];
        }
    }
}

// ---- Kernel 3: 16-block rowlse + atomic final sum -------------------------
__global__ __launch_bounds__(256) void k_rowlse(
    const float* __restrict__ partial, const float* __restrict__ posv,
    float* __restrict__ out) {
    __shared__ float red[4];
    const int tid = threadIdx.x;
    const int row = blockIdx.x * 256 + tid;
    float s = 0.f;
    #pragma unroll
    for (int p = 0; p < NCB; ++p) s += partial[p * NROWS + row];
    float v = __logf(s) - posv[row];
    #pragma unroll
    for (int m = 1; m < 64; m <<= 1) v += __shfl_xor(v, m);
    if ((tid & 63) == 0) red[tid >> 6] = v;
    __syncthreads();
    if (tid == 0)
        atomicAdd(out, (red[0] + red[1] + red[2] + red[3]) * (1.0f / (float)NROWS));
}

extern "C" void kernel_launch(void* const* d_in, const int* in_sizes, int n_in,
                              void* d_out, int out_size, void* d_ws, size_t ws_size,
                              hipStream_t stream) {
    const float* zi = (const float*)d_in[0];
    const float* zj = (const float*)d_in[1];
    float* out = (float*)d_out;

    unsigned short* zn = (unsigned short*)d_ws;                    // 2 MB
    float* partial = (float*)((char*)d_ws + NROWS * DDIM * 2);     // 512 KB
    float* posv = partial + NCB * NROWS;                           // 16 KB

    k_normalize<<<NROWS / 4, 256, 0, stream>>>(zi, zj, zn, out);
    k_simlse<<<NCB * (NCB + 1) / 2, 256, 0, stream>>>(zn, partial, posv);
    k_rowlse<<<16, 256, 0, stream>>>(partial, posv, out);
}